// Round 7
// baseline (1449.704 us; speedup 1.0000x reference)
//
#include <hip/hip_runtime.h>
#include <cstdint>
#include <cstddef>

#define HDIM 128
#define INDIM 256
#define RANK 4
#define NLAYER 2
#define PELEN 2000

#define BM 128      // rows per block
#define BK 32       // k-chunk
#define TLD 132     // LDS tile leading dim (128 + 4)

constexpr float SCALING_F = 2.0f;   // 8.0/4.0
constexpr float EPS_LN = 1e-5f;

// ================= graph prep =================

__global__ void deg_kernel(const int* __restrict__ src, const int* __restrict__ dst,
                           int* __restrict__ dego, int* __restrict__ degi, int E) {
    int e = blockIdx.x * 256 + threadIdx.x;
    if (e < E) {
        atomicAdd(&dego[src[e]], 1);
        atomicAdd(&degi[dst[e]], 1);
    }
}

__global__ void norm_kernel(const int* __restrict__ dego, const int* __restrict__ degi,
                            float* __restrict__ nout, float* __restrict__ nin, int N) {
    int i = blockIdx.x * 256 + threadIdx.x;
    if (i < N) {
        int a = dego[i];
        nout[i] = (a > 0) ? rsqrtf((float)a) : 0.0f;
        int b = degi[i];
        nin[i]  = (b > 0) ? rsqrtf((float)b) : 0.0f;
    }
}

__global__ __launch_bounds__(256) void scan1_kernel(const int* __restrict__ degi,
                                                    int* __restrict__ sincl,
                                                    int* __restrict__ bsum, int N) {
    int i = blockIdx.x * 256 + threadIdx.x;
    int lane = threadIdx.x & 63;
    int w = threadIdx.x >> 6;
    int x = (i < N) ? degi[i] : 0;
#pragma unroll
    for (int d = 1; d < 64; d <<= 1) {
        int y = __shfl_up(x, d);
        if (lane >= d) x += y;
    }
    __shared__ int wsum[4];
    if (lane == 63) wsum[w] = x;
    __syncthreads();
    int add = 0;
    for (int j = 0; j < w; ++j) add += wsum[j];
    x += add;
    if (i < N) sincl[i] = x;
    if (threadIdx.x == 255) bsum[blockIdx.x] = x;
}

__global__ __launch_bounds__(512) void scan2_kernel(int* __restrict__ bsum, int NB) {
    int i = threadIdx.x;
    int lane = i & 63;
    int w = i >> 6;
    int x = (i < NB) ? bsum[i] : 0;
#pragma unroll
    for (int d = 1; d < 64; d <<= 1) {
        int y = __shfl_up(x, d);
        if (lane >= d) x += y;
    }
    __shared__ int wsum[8];
    if (lane == 63) wsum[w] = x;
    __syncthreads();
    int add = 0;
    for (int j = 0; j < w; ++j) add += wsum[j];
    x += add;
    if (i < NB) bsum[i] = x;
}

__global__ __launch_bounds__(256) void scan3_kernel(const int* __restrict__ degi,
                                                    const int* __restrict__ sincl,
                                                    const int* __restrict__ bsum,
                                                    int* __restrict__ row_ptr,
                                                    int* __restrict__ cursor, int N) {
    int i = blockIdx.x * 256 + threadIdx.x;
    if (i >= N) return;
    int b = blockIdx.x;
    int incl = sincl[i] + ((b > 0) ? bsum[b - 1] : 0);
    int excl = incl - degi[i];
    row_ptr[i] = excl;
    cursor[i] = excl;
    if (i == N - 1) row_ptr[N] = incl;
}

__global__ void place_kernel(const int* __restrict__ src, const int* __restrict__ dst,
                             int* __restrict__ cursor, int* __restrict__ csr_src, int E) {
    int e = blockIdx.x * 256 + threadIdx.x;
    if (e < E) {
        int d = dst[e];
        int pos = atomicAdd(&cursor[d], 1);
        csr_src[pos] = src[e];
    }
}

// agg[n] = nin[n] * sum_{e: dst=n} h[src]*nout[src]
__global__ __launch_bounds__(256) void gather_kernel(
        const float* __restrict__ h, const float* __restrict__ nout,
        const float* __restrict__ nin, const int* __restrict__ row_ptr,
        const int* __restrict__ csr_src, float* __restrict__ agg, int N) {
    int node = blockIdx.x * 4 + (threadIdx.x >> 6);
    if (node >= N) return;
    int lane = threadIdx.x & 63;
    int start = row_ptr[node], end = row_ptr[node + 1];
    const float2* h2 = (const float2*)h;
    float2 acc = make_float2(0.f, 0.f);
    int i = start;
    for (; i + 2 <= end; i += 2) {
        int s0 = csr_src[i], s1 = csr_src[i + 1];
        float n0 = nout[s0], n1 = nout[s1];
        float2 v0 = h2[(size_t)s0 * 64 + lane];
        float2 v1 = h2[(size_t)s1 * 64 + lane];
        acc.x += v0.x * n0; acc.y += v0.y * n0;
        acc.x += v1.x * n1; acc.y += v1.y * n1;
    }
    if (i < end) {
        int s = csr_src[i];
        float n = nout[s];
        float2 v = h2[(size_t)s * 64 + lane];
        acc.x += v.x * n; acc.y += v.y * n;
    }
    float ni = nin[node];
    ((float2*)agg)[(size_t)node * 64 + lane] = make_float2(acc.x * ni, acc.y * ni);
}

// ================= GEMM building blocks (BM=128, 512 threads) =================

// ---- register loaders (issue global loads; consumed next step) ----
__device__ __forceinline__ void load_x(const float* __restrict__ X, int ldx, int brow,
                                       int k0, int N, int tid, float4& a, float4& b) {
    int rr = tid & 127, kc = tid >> 7;           // kc 0..3, 8-col chunk
    int row = brow + rr;
    a = make_float4(0.f, 0.f, 0.f, 0.f); b = a;
    if (row < N) {
        const float4* s = (const float4*)(X + (size_t)row * ldx + k0 + kc * 8);
        a = s[0]; b = s[1];
    }
}
__device__ __forceinline__ void store_x(int tid, const float4& a, const float4& b,
                                        float xt[BK][TLD]) {
    int rr = tid & 127, kb = (tid >> 7) * 8;
    xt[kb + 0][rr] = a.x; xt[kb + 1][rr] = a.y; xt[kb + 2][rr] = a.z; xt[kb + 3][rr] = a.w;
    xt[kb + 4][rr] = b.x; xt[kb + 5][rr] = b.y; xt[kb + 6][rr] = b.z; xt[kb + 7][rr] = b.w;
}

// W[128][ldw] row-major used as x@W.T  -> wt[kk][n]
__device__ __forceinline__ void load_wT(const float* __restrict__ W, int ldw,
                                        int k0, int tid, float4& a, float4& b) {
    int n = tid & 127, q = tid >> 7;
    const float4* s = (const float4*)(W + (size_t)n * ldw + k0 + q * 8);
    a = s[0]; b = s[1];
}
__device__ __forceinline__ void store_wT(int tid, const float4& a, const float4& b,
                                         float wt[BK][TLD]) {
    int n = tid & 127, kb = (tid >> 7) * 8;
    wt[kb + 0][n] = a.x; wt[kb + 1][n] = a.y; wt[kb + 2][n] = a.z; wt[kb + 3][n] = a.w;
    wt[kb + 4][n] = b.x; wt[kb + 5][n] = b.y; wt[kb + 6][n] = b.z; wt[kb + 7][n] = b.w;
}

// W[K][128] row-major used as x@W  -> wt[kk][n]
__device__ __forceinline__ void load_wD(const float* __restrict__ W,
                                        int k0, int tid, float4& a, float4& b) {
    int kk = tid >> 4, nc = tid & 15;
    const float4* s = (const float4*)(W + (size_t)(k0 + kk) * HDIM + nc * 8);
    a = s[0]; b = s[1];
}
__device__ __forceinline__ void store_wD(int tid, const float4& a, const float4& b,
                                         float wt[BK][TLD]) {
    int kk = tid >> 4, nc = tid & 15;
    *(float4*)&wt[kk][nc * 8]     = a;
    *(float4*)&wt[kk][nc * 8 + 4] = b;
}

// inner: acc[4][8] += xt[k][r0..r0+3] x wt[k][c0..c0+7]
__device__ __forceinline__ void mm_inner(const float xt[BK][TLD], const float wt[BK][TLD],
                                         int r0, int c0, float acc[4][8]) {
#pragma unroll
    for (int kk = 0; kk < BK; ++kk) {
        float4 a  = *(const float4*)&xt[kk][r0];
        float4 b0 = *(const float4*)&wt[kk][c0];
        float4 b1 = *(const float4*)&wt[kk][c0 + 4];
        float av[4] = {a.x, a.y, a.z, a.w};
        float bv[8] = {b0.x, b0.y, b0.z, b0.w, b1.x, b1.y, b1.z, b1.w};
#pragma unroll
        for (int i = 0; i < 4; ++i)
#pragma unroll
            for (int j = 0; j < 8; ++j)
                acc[i][j] = fmaf(av[i], bv[j], acc[i][j]);
    }
}

// lora partial: tacc += sum_kk xt[kk][lrow] * A[lq][k0+kk]
__device__ __forceinline__ float lora_part(const float xt[BK][TLD],
                                           const float* __restrict__ A, int ldA,
                                           int k0, int lrow, int lq) {
    const float* Arow = A + (size_t)lq * ldA + k0;
    float p = 0.f;
#pragma unroll
    for (int q4 = 0; q4 < BK / 4; ++q4) {
        float4 av = *(const float4*)(Arow + q4 * 4);
        p = fmaf(xt[q4 * 4 + 0][lrow], av.x, p);
        p = fmaf(xt[q4 * 4 + 1][lrow], av.y, p);
        p = fmaf(xt[q4 * 4 + 2][lrow], av.z, p);
        p = fmaf(xt[q4 * 4 + 3][lrow], av.w, p);
    }
    return p;
}

// ================= input projection =================
// h = feats@Win.T + bin + SCALING*(feats@Ain.T)@Bin.T + pe[min(row,1999)]

__global__ __launch_bounds__(512) void input_kernel(
        const float* __restrict__ feats, const float* __restrict__ pe,
        const float* __restrict__ Win, const float* __restrict__ bin,
        const float* __restrict__ Ain, const float* __restrict__ Bin,
        float* __restrict__ h, int N) {
    __shared__ float xt[BK][TLD];
    __shared__ float wt[BK][TLD];
    __shared__ float ts[BM][RANK];
    int brow = blockIdx.x * BM;
    int tid = threadIdx.x;
    int rg = tid >> 4, cg = tid & 15;
    int r0 = rg * 4, c0 = cg * 8;
    int lrow = tid >> 2, lq = tid & 3;

    float acc[4][8] = {};
    float tacc = 0.f;
    float4 xa, xb, wa, wb;

    load_x(feats, INDIM, brow, 0, N, tid, xa, xb);
    load_wT(Win, INDIM, 0, tid, wa, wb);

    for (int s = 0; s < INDIM / BK; ++s) {
        __syncthreads();
        store_x(tid, xa, xb, xt);
        store_wT(tid, wa, wb, wt);
        __syncthreads();
        if (s + 1 < INDIM / BK) {
            load_x(feats, INDIM, brow, (s + 1) * BK, N, tid, xa, xb);
            load_wT(Win, INDIM, (s + 1) * BK, tid, wa, wb);
        }
        tacc += lora_part(xt, Ain, INDIM, s * BK, lrow, lq);
        mm_inner(xt, wt, r0, c0, acc);
    }
    ts[lrow][lq] = tacc;
    __syncthreads();

#pragma unroll
    for (int i = 0; i < 4; ++i) {
        int row = brow + r0 + i;
        if (row >= N) break;
        float4 tq = *(const float4*)&ts[r0 + i][0];
        int pos = (row < PELEN) ? row : (PELEN - 1);
        const float* per = pe + (size_t)pos * HDIM;
        float o[8];
#pragma unroll
        for (int j = 0; j < 8; ++j) {
            int c = c0 + j;
            float lo = tq.x * Bin[c * RANK + 0] + tq.y * Bin[c * RANK + 1]
                     + tq.z * Bin[c * RANK + 2] + tq.w * Bin[c * RANK + 3];
            o[j] = acc[i][j] + bin[c] + per[c] + SCALING_F * lo;
        }
        float* ho = h + (size_t)row * HDIM + c0;
        *(float4*)(ho)     = make_float4(o[0], o[1], o[2], o[3]);
        *(float4*)(ho + 4) = make_float4(o[4], o[5], o[6], o[7]);
    }
}

// ================= fused layer =================
// h += gelu(LN(agg@gW + gb + h@lW.T + lb + SCALING*(h@lA.T)@lB.T))
// 8 pipelined steps: 0-3 = agg@gW (wD), 4-7 = h@lW.T (wT) + lora

__global__ __launch_bounds__(512) void layer_kernel(
        float* __restrict__ h, const float* __restrict__ agg,
        const float* __restrict__ gW, const float* __restrict__ gb,
        const float* __restrict__ lWp, const float* __restrict__ lbp,
        const float* __restrict__ lAp, const float* __restrict__ lBp,
        const float* __restrict__ gammap, const float* __restrict__ betap, int N) {
    __shared__ float xt[BK][TLD];
    __shared__ float wt[BK][TLD];
    __shared__ float ts[BM][RANK];
    int brow = blockIdx.x * BM;
    int tid = threadIdx.x;
    int rg = tid >> 4, cg = tid & 15;
    int r0 = rg * 4, c0 = cg * 8;
    int lrow = tid >> 2, lq = tid & 3;

    float acc[4][8] = {};
    float tacc = 0.f;
    float4 xa, xb, wa, wb;

    load_x(agg, HDIM, brow, 0, N, tid, xa, xb);
    load_wD(gW, 0, tid, wa, wb);

    for (int s = 0; s < 8; ++s) {
        __syncthreads();
        store_x(tid, xa, xb, xt);
        if (s < 4) store_wD(tid, wa, wb, wt);
        else       store_wT(tid, wa, wb, wt);
        __syncthreads();
        int ns = s + 1;
        if (ns < 4) {
            load_x(agg, HDIM, brow, ns * BK, N, tid, xa, xb);
            load_wD(gW, ns * BK, tid, wa, wb);
        } else if (ns < 8) {
            load_x(h, HDIM, brow, (ns - 4) * BK, N, tid, xa, xb);
            load_wT(lWp, HDIM, (ns - 4) * BK, tid, wa, wb);
        }
        if (s >= 4) tacc += lora_part(xt, lAp, HDIM, (s - 4) * BK, lrow, lq);
        mm_inner(xt, wt, r0, c0, acc);
    }
    ts[lrow][lq] = tacc;
    __syncthreads();

#pragma unroll
    for (int i = 0; i < 4; ++i) {
        int row = brow + r0 + i;
        if (row >= N) continue;
        float4 tq = *(const float4*)&ts[r0 + i][0];
        float val[8];
#pragma unroll
        for (int j = 0; j < 8; ++j) {
            int c = c0 + j;
            float lo = tq.x * lBp[c * RANK + 0] + tq.y * lBp[c * RANK + 1]
                     + tq.z * lBp[c * RANK + 2] + tq.w * lBp[c * RANK + 3];
            val[j] = acc[i][j] + gb[c] + lbp[c] + SCALING_F * lo;
        }
        // LayerNorm across the 16 cg lanes (each holds 8 of 128)
        float ssum = 0.f;
#pragma unroll
        for (int j = 0; j < 8; ++j) ssum += val[j];
#pragma unroll
        for (int m = 8; m >= 1; m >>= 1) ssum += __shfl_xor(ssum, m);
        float mu = ssum * (1.0f / HDIM);
        float vsum = 0.f;
#pragma unroll
        for (int j = 0; j < 8; ++j) { float d = val[j] - mu; vsum += d * d; }
#pragma unroll
        for (int m = 8; m >= 1; m >>= 1) vsum += __shfl_xor(vsum, m);
        float rstd = rsqrtf(vsum * (1.0f / HDIM) + EPS_LN);

        float* ho = h + (size_t)row * HDIM + c0;
        float4 h0 = *(const float4*)(ho);
        float4 h1 = *(const float4*)(ho + 4);
        float hold[8] = {h0.x, h0.y, h0.z, h0.w, h1.x, h1.y, h1.z, h1.w};
        float o[8];
#pragma unroll
        for (int j = 0; j < 8; ++j) {
            int c = c0 + j;
            float y = (val[j] - mu) * rstd * gammap[c] + betap[c];
            float g = 0.5f * y * (1.0f + erff(y * 0.70710678118654752f));
            o[j] = hold[j] + g;
        }
        *(float4*)(ho)     = make_float4(o[0], o[1], o[2], o[3]);
        *(float4*)(ho + 4) = make_float4(o[4], o[5], o[6], o[7]);
    }
}

// ================= output projection =================

__global__ __launch_bounds__(512) void out_kernel(
        const float* __restrict__ h,
        const float* __restrict__ W, const float* __restrict__ b,
        const float* __restrict__ A, const float* __restrict__ B,
        float* __restrict__ out, int N) {
    __shared__ float xt[BK][TLD];
    __shared__ float wt[BK][TLD];
    __shared__ float ts[BM][RANK];
    int brow = blockIdx.x * BM;
    int tid = threadIdx.x;
    int rg = tid >> 4, cg = tid & 15;
    int r0 = rg * 4, c0 = cg * 8;
    int lrow = tid >> 2, lq = tid & 3;

    float acc[4][8] = {};
    float tacc = 0.f;
    float4 xa, xb, wa, wb;

    load_x(h, HDIM, brow, 0, N, tid, xa, xb);
    load_wT(W, HDIM, 0, tid, wa, wb);

    for (int s = 0; s < HDIM / BK; ++s) {
        __syncthreads();
        store_x(tid, xa, xb, xt);
        store_wT(tid, wa, wb, wt);
        __syncthreads();
        if (s + 1 < HDIM / BK) {
            load_x(h, HDIM, brow, (s + 1) * BK, N, tid, xa, xb);
            load_wT(W, HDIM, (s + 1) * BK, tid, wa, wb);
        }
        tacc += lora_part(xt, A, HDIM, s * BK, lrow, lq);
        mm_inner(xt, wt, r0, c0, acc);
    }
    ts[lrow][lq] = tacc;
    __syncthreads();

#pragma unroll
    for (int i = 0; i < 4; ++i) {
        int row = brow + r0 + i;
        if (row >= N) break;
        float4 tq = *(const float4*)&ts[r0 + i][0];
        float o[8];
#pragma unroll
        for (int j = 0; j < 8; ++j) {
            int c = c0 + j;
            float lo = tq.x * B[c * RANK + 0] + tq.y * B[c * RANK + 1]
                     + tq.z * B[c * RANK + 2] + tq.w * B[c * RANK + 3];
            o[j] = acc[i][j] + b[c] + SCALING_F * lo;
        }
        float* oo = out + (size_t)row * HDIM + c0;
        *(float4*)(oo)     = make_float4(o[0], o[1], o[2], o[3]);
        *(float4*)(oo + 4) = make_float4(o[4], o[5], o[6], o[7]);
    }
}

// ================= launch =================

extern "C" void kernel_launch(void* const* d_in, const int* in_sizes, int n_in,
                              void* d_out, int out_size, void* d_ws, size_t ws_size,
                              hipStream_t stream) {
    const float* features = (const float*)d_in[0];
    const int*   esrc     = (const int*)d_in[1];
    const int*   edst     = (const int*)d_in[2];
    const float* pe       = (const float*)d_in[3];
    const float* W_in     = (const float*)d_in[4];
    const float* b_in     = (const float*)d_in[5];
    const float* A_in     = (const float*)d_in[6];
    const float* B_in     = (const float*)d_in[7];
    const float* gnn_W    = (const float*)d_in[8];
    const float* gnn_b    = (const float*)d_in[9];
    const float* lW       = (const float*)d_in[10];
    const float* lb       = (const float*)d_in[11];
    const float* lA       = (const float*)d_in[12];
    const float* lB       = (const float*)d_in[13];
    const float* gamma    = (const float*)d_in[14];
    const float* beta     = (const float*)d_in[15];
    const float* W_out    = (const float*)d_in[16];
    const float* b_out    = (const float*)d_in[17];
    const float* A_out    = (const float*)d_in[18];
    const float* B_out    = (const float*)d_in[19];

    int N = in_sizes[0] / INDIM;   // 100000
    int E = in_sizes[1];           // 1,700,000
    int NB = (N + 255) / 256;

    // workspace layout
    char* ws = (char*)d_ws;
    float* h       = (float*)ws;                               // N*H
    float* agg     = h + (size_t)N * HDIM;                     // N*H
    int*   dego    = (int*)(agg + (size_t)N * HDIM);           // N
    int*   degi    = dego + N;                                 // N
    float* nout    = (float*)(degi + N);                       // N
    float* nin     = nout + N;                                 // N
    int*   row_ptr = (int*)(nin + N);                          // N+1
    int*   cursor  = row_ptr + N + 1;                          // N
    int*   sincl   = cursor + N;                               // N
    int*   bsum    = sincl + N;                                // NB
    int*   csr_src = bsum + NB;                                // E

    hipMemsetAsync(dego, 0, 2 * (size_t)N * sizeof(int), stream);
    deg_kernel<<<(E + 255) / 256, 256, 0, stream>>>(esrc, edst, dego, degi, E);
    norm_kernel<<<NB, 256, 0, stream>>>(dego, degi, nout, nin, N);

    scan1_kernel<<<NB, 256, 0, stream>>>(degi, sincl, bsum, N);
    scan2_kernel<<<1, 512, 0, stream>>>(bsum, NB);
    scan3_kernel<<<NB, 256, 0, stream>>>(degi, sincl, bsum, row_ptr, cursor, N);
    place_kernel<<<(E + 255) / 256, 256, 0, stream>>>(esrc, edst, cursor, csr_src, E);

    int gemm_grid = (N + BM - 1) / BM;   // 782
    input_kernel<<<gemm_grid, 512, 0, stream>>>(features, pe, W_in, b_in, A_in, B_in, h, N);

    for (int i = 0; i < NLAYER; ++i) {
        gather_kernel<<<(N + 3) / 4, 256, 0, stream>>>(h, nout, nin, row_ptr, csr_src, agg, N);
        layer_kernel<<<gemm_grid, 512, 0, stream>>>(
            h, agg,
            gnn_W + (size_t)i * HDIM * HDIM, gnn_b + (size_t)i * HDIM,
            lW + (size_t)i * HDIM * HDIM, lb + (size_t)i * HDIM,
            lA + (size_t)i * RANK * HDIM, lB + (size_t)i * HDIM * RANK,
            gamma + (size_t)i * HDIM, beta + (size_t)i * HDIM, N);
    }

    out_kernel<<<gemm_grid, 512, 0, stream>>>(h, W_out, b_out, A_out, B_out, (float*)d_out, N);
}

// Round 9
// 1107.321 us; speedup vs baseline: 1.3092x; 1.3092x over previous
//
#include <hip/hip_runtime.h>
#include <cstdint>
#include <cstddef>

#define HDIM 128
#define INDIM 256
#define RANK 4
#define NLAYER 2
#define PELEN 2000

#define BM 64
#define BK 32
#define XT_LD 68    // BM + 4 pad
#define WT_LD 132   // 128 + 4 pad

constexpr float SCALING_F = 2.0f;   // 8.0/4.0
constexpr float EPS_LN = 1e-5f;

// ================= graph prep =================

__global__ void deg_kernel(const int* __restrict__ src, const int* __restrict__ dst,
                           int* __restrict__ dego, int* __restrict__ degi, int E) {
    int e = blockIdx.x * 256 + threadIdx.x;
    if (e < E) {
        atomicAdd(&dego[src[e]], 1);
        atomicAdd(&degi[dst[e]], 1);
    }
}

__global__ void norm_kernel(const int* __restrict__ dego, const int* __restrict__ degi,
                            float* __restrict__ nout, float* __restrict__ nin, int N) {
    int i = blockIdx.x * 256 + threadIdx.x;
    if (i < N) {
        int a = dego[i];
        nout[i] = (a > 0) ? rsqrtf((float)a) : 0.0f;
        int b = degi[i];
        nin[i]  = (b > 0) ? rsqrtf((float)b) : 0.0f;
    }
}

__global__ __launch_bounds__(256) void scan1_kernel(const int* __restrict__ degi,
                                                    int* __restrict__ sincl,
                                                    int* __restrict__ bsum, int N) {
    int i = blockIdx.x * 256 + threadIdx.x;
    int lane = threadIdx.x & 63;
    int w = threadIdx.x >> 6;
    int x = (i < N) ? degi[i] : 0;
#pragma unroll
    for (int d = 1; d < 64; d <<= 1) {
        int y = __shfl_up(x, d);
        if (lane >= d) x += y;
    }
    __shared__ int wsum[4];
    if (lane == 63) wsum[w] = x;
    __syncthreads();
    int add = 0;
    for (int j = 0; j < w; ++j) add += wsum[j];
    x += add;
    if (i < N) sincl[i] = x;
    if (threadIdx.x == 255) bsum[blockIdx.x] = x;
}

__global__ __launch_bounds__(512) void scan2_kernel(int* __restrict__ bsum, int NB) {
    int i = threadIdx.x;
    int lane = i & 63;
    int w = i >> 6;
    int x = (i < NB) ? bsum[i] : 0;
#pragma unroll
    for (int d = 1; d < 64; d <<= 1) {
        int y = __shfl_up(x, d);
        if (lane >= d) x += y;
    }
    __shared__ int wsum[8];
    if (lane == 63) wsum[w] = x;
    __syncthreads();
    int add = 0;
    for (int j = 0; j < w; ++j) add += wsum[j];
    x += add;
    if (i < NB) bsum[i] = x;
}

__global__ __launch_bounds__(256) void scan3_kernel(const int* __restrict__ degi,
                                                    const int* __restrict__ sincl,
                                                    const int* __restrict__ bsum,
                                                    int* __restrict__ row_ptr,
                                                    int* __restrict__ cursor, int N) {
    int i = blockIdx.x * 256 + threadIdx.x;
    if (i >= N) return;
    int b = blockIdx.x;
    int incl = sincl[i] + ((b > 0) ? bsum[b - 1] : 0);
    int excl = incl - degi[i];
    row_ptr[i] = excl;
    cursor[i] = excl;
    if (i == N - 1) row_ptr[N] = incl;
}

__global__ void place_kernel(const int* __restrict__ src, const int* __restrict__ dst,
                             int* __restrict__ cursor, int* __restrict__ csr_src, int E) {
    int e = blockIdx.x * 256 + threadIdx.x;
    if (e < E) {
        int d = dst[e];
        int pos = atomicAdd(&cursor[d], 1);
        csr_src[pos] = src[e];
    }
}

// agg[n] = nin[n] * sum_{e: dst=n} h[src]*nout[src]
__global__ __launch_bounds__(256) void gather_kernel(
        const float* __restrict__ h, const float* __restrict__ nout,
        const float* __restrict__ nin, const int* __restrict__ row_ptr,
        const int* __restrict__ csr_src, float* __restrict__ agg, int N) {
    int node = blockIdx.x * 4 + (threadIdx.x >> 6);
    if (node >= N) return;
    int lane = threadIdx.x & 63;
    int start = row_ptr[node], end = row_ptr[node + 1];
    const float2* h2 = (const float2*)h;
    float2 acc = make_float2(0.f, 0.f);
    int i = start;
    for (; i + 4 <= end; i += 4) {
        int s0 = csr_src[i], s1 = csr_src[i + 1], s2 = csr_src[i + 2], s3 = csr_src[i + 3];
        float n0 = nout[s0], n1 = nout[s1], n2 = nout[s2], n3 = nout[s3];
        float2 v0 = h2[(size_t)s0 * 64 + lane];
        float2 v1 = h2[(size_t)s1 * 64 + lane];
        float2 v2 = h2[(size_t)s2 * 64 + lane];
        float2 v3 = h2[(size_t)s3 * 64 + lane];
        acc.x += v0.x * n0; acc.y += v0.y * n0;
        acc.x += v1.x * n1; acc.y += v1.y * n1;
        acc.x += v2.x * n2; acc.y += v2.y * n2;
        acc.x += v3.x * n3; acc.y += v3.y * n3;
    }
    for (; i < end; ++i) {
        int s = csr_src[i];
        float n = nout[s];
        float2 v = h2[(size_t)s * 64 + lane];
        acc.x += v.x * n; acc.y += v.y * n;
    }
    float ni = nin[node];
    ((float2*)agg)[(size_t)node * 64 + lane] = make_float2(acc.x * ni, acc.y * ni);
}

// ================= tiled GEMM building blocks =================

// stage X[brow..brow+63][k0..k0+31] -> xt[kk][row] (transposed)
__device__ __forceinline__ void stage_x(const float* __restrict__ X, int ldx, int brow,
                                        int k0, int N, int tid, float xt[BK][XT_LD]) {
    int rr = tid & 63;        // row within tile
    int kc = tid >> 6;        // 0..3, 8-float column chunk
    int row = brow + rr;
    float4 v0 = make_float4(0.f, 0.f, 0.f, 0.f), v1 = v0;
    if (row < N) {
        const float4* s = (const float4*)(X + (size_t)row * ldx + k0 + kc * 8);
        v0 = s[0]; v1 = s[1];
    }
    int kb = kc * 8;
    xt[kb + 0][rr] = v0.x; xt[kb + 1][rr] = v0.y; xt[kb + 2][rr] = v0.z; xt[kb + 3][rr] = v0.w;
    xt[kb + 4][rr] = v1.x; xt[kb + 5][rr] = v1.y; xt[kb + 6][rr] = v1.z; xt[kb + 7][rr] = v1.w;
}

// stage W[n][k0..k0+31] ([128][ldw] row-major, used as x@W.T) -> wt[kk][n]
__device__ __forceinline__ void stage_wT(const float* __restrict__ W, int ldw,
                                         int k0, int tid, float wt[BK][WT_LD]) {
    int n = tid >> 1, half = tid & 1;
    const float4* s = (const float4*)(W + (size_t)n * ldw + k0 + half * 16);
    float4 a = s[0], b = s[1], c = s[2], d = s[3];
    int kb = half * 16;
    wt[kb +  0][n] = a.x; wt[kb +  1][n] = a.y; wt[kb +  2][n] = a.z; wt[kb +  3][n] = a.w;
    wt[kb +  4][n] = b.x; wt[kb +  5][n] = b.y; wt[kb +  6][n] = b.z; wt[kb +  7][n] = b.w;
    wt[kb +  8][n] = c.x; wt[kb +  9][n] = c.y; wt[kb + 10][n] = c.z; wt[kb + 11][n] = c.w;
    wt[kb + 12][n] = d.x; wt[kb + 13][n] = d.y; wt[kb + 14][n] = d.z; wt[kb + 15][n] = d.w;
}

// stage W[k0..k0+31][0..127] ([K][128] row-major, used as x@W) -> wt[kk][n]
__device__ __forceinline__ void stage_wD(const float* __restrict__ W,
                                         int k0, int tid, float wt[BK][WT_LD]) {
    int kk = tid >> 3, nc = tid & 7;
    const float4* s = (const float4*)(W + (size_t)(k0 + kk) * HDIM);
#pragma unroll
    for (int j = 0; j < 4; ++j) {
        float4 v = s[nc + 8 * j];
        *(float4*)&wt[kk][(nc + 8 * j) * 4] = v;
    }
}

// inner: acc[4][8] over rows r0..r0+3 and cols {c0a..c0a+3, c0a+64..c0a+67}
// c0a = cg*4 -> lane stride 16B on wt reads: 2-way bank aliasing (free), was 4-way at c0=cg*8
__device__ __forceinline__ void mm_inner(const float xt[BK][XT_LD], const float wt[BK][WT_LD],
                                         int r0, int c0a, float acc[4][8]) {
#pragma unroll
    for (int kk = 0; kk < BK; ++kk) {
        float4 a  = *(const float4*)&xt[kk][r0];
        float4 b0 = *(const float4*)&wt[kk][c0a];
        float4 b1 = *(const float4*)&wt[kk][c0a + 64];
        float av[4] = {a.x, a.y, a.z, a.w};
        float bv[8] = {b0.x, b0.y, b0.z, b0.w, b1.x, b1.y, b1.z, b1.w};
#pragma unroll
        for (int i = 0; i < 4; ++i)
#pragma unroll
            for (int j = 0; j < 8; ++j)
                acc[i][j] = fmaf(av[i], bv[j], acc[i][j]);
    }
}

// lora partial: tacc += sum_kk xt[kk][lrow] * A[lq][k0+kk]
__device__ __forceinline__ float lora_part(const float xt[BK][XT_LD],
                                           const float* __restrict__ A, int ldA,
                                           int k0, int lrow, int lq) {
    const float* Arow = A + (size_t)lq * ldA + k0;
    float p = 0.f;
#pragma unroll
    for (int q4 = 0; q4 < BK / 4; ++q4) {
        float4 av = *(const float4*)(Arow + q4 * 4);
        p = fmaf(xt[q4 * 4 + 0][lrow], av.x, p);
        p = fmaf(xt[q4 * 4 + 1][lrow], av.y, p);
        p = fmaf(xt[q4 * 4 + 2][lrow], av.z, p);
        p = fmaf(xt[q4 * 4 + 3][lrow], av.w, p);
    }
    return p;
}

// column of acc slot j for a thread with c0a = cg*4
__device__ __forceinline__ int col_of(int c0a, int j) {
    return (j < 4) ? (c0a + j) : (c0a + 64 + (j - 4));
}

// ================= input projection =================
// h = feats@Win.T + bin + SCALING*(feats@Ain.T)@Bin.T + pe[min(row,1999)]

__global__ __launch_bounds__(256) void input_kernel(
        const float* __restrict__ feats, const float* __restrict__ pe,
        const float* __restrict__ Win, const float* __restrict__ bin,
        const float* __restrict__ Ain, const float* __restrict__ Bin,
        float* __restrict__ h, int N) {
    __shared__ float xt[BK][XT_LD];
    __shared__ float wt[BK][WT_LD];
    __shared__ float ts[BM][RANK];
    int brow = blockIdx.x * BM;
    int tid = threadIdx.x;
    int rg = tid >> 4, cg = tid & 15;
    int r0 = rg * 4, c0a = cg * 4;
    int lrow = tid >> 2, lq = tid & 3;

    float acc[4][8] = {};
    float tacc = 0.f;

    for (int k0 = 0; k0 < INDIM; k0 += BK) {
        __syncthreads();
        stage_x(feats, INDIM, brow, k0, N, tid, xt);
        stage_wT(Win, INDIM, k0, tid, wt);
        __syncthreads();
        tacc += lora_part(xt, Ain, INDIM, k0, lrow, lq);
        mm_inner(xt, wt, r0, c0a, acc);
    }
    ts[lrow][lq] = tacc;
    __syncthreads();

#pragma unroll
    for (int i = 0; i < 4; ++i) {
        int row = brow + r0 + i;
        if (row >= N) break;
        float4 tq = *(const float4*)&ts[r0 + i][0];
        int pos = (row < PELEN) ? row : (PELEN - 1);
        const float* per = pe + (size_t)pos * HDIM;
        float o[8];
#pragma unroll
        for (int j = 0; j < 8; ++j) {
            int c = col_of(c0a, j);
            float lo = tq.x * Bin[c * RANK + 0] + tq.y * Bin[c * RANK + 1]
                     + tq.z * Bin[c * RANK + 2] + tq.w * Bin[c * RANK + 3];
            o[j] = acc[i][j] + bin[c] + per[c] + SCALING_F * lo;
        }
        float* ho = h + (size_t)row * HDIM;
        *(float4*)(ho + c0a)      = make_float4(o[0], o[1], o[2], o[3]);
        *(float4*)(ho + c0a + 64) = make_float4(o[4], o[5], o[6], o[7]);
    }
}

// ================= fused layer =================
// h += gelu(LN(agg@gW + gb + h@lW.T + lb + SCALING*(h@lA.T)@lB.T))

__global__ __launch_bounds__(256) void layer_kernel(
        float* __restrict__ h, const float* __restrict__ agg,
        const float* __restrict__ gW, const float* __restrict__ gb,
        const float* __restrict__ lWp, const float* __restrict__ lbp,
        const float* __restrict__ lAp, const float* __restrict__ lBp,
        const float* __restrict__ gammap, const float* __restrict__ betap, int N) {
    __shared__ float xt[BK][XT_LD];
    __shared__ float wt[BK][WT_LD];
    __shared__ float ts[BM][RANK];
    int brow = blockIdx.x * BM;
    int tid = threadIdx.x;
    int rg = tid >> 4, cg = tid & 15;
    int r0 = rg * 4, c0a = cg * 4;
    int lrow = tid >> 2, lq = tid & 3;

    float acc[4][8] = {};
    float tacc = 0.f;

    // pass 1: agg @ gW  (gW is [K][128] direct)
    for (int k0 = 0; k0 < HDIM; k0 += BK) {
        __syncthreads();
        stage_x(agg, HDIM, brow, k0, N, tid, xt);
        stage_wD(gW, k0, tid, wt);
        __syncthreads();
        mm_inner(xt, wt, r0, c0a, acc);
    }
    // pass 2: h @ lW.T  (+ lora partials on h)
    for (int k0 = 0; k0 < HDIM; k0 += BK) {
        __syncthreads();
        stage_x(h, HDIM, brow, k0, N, tid, xt);
        stage_wT(lWp, HDIM, k0, tid, wt);
        __syncthreads();
        tacc += lora_part(xt, lAp, HDIM, k0, lrow, lq);
        mm_inner(xt, wt, r0, c0a, acc);
    }
    ts[lrow][lq] = tacc;
    __syncthreads();

#pragma unroll
    for (int i = 0; i < 4; ++i) {
        int row = brow + r0 + i;
        if (row >= N) continue;
        float4 tq = *(const float4*)&ts[r0 + i][0];
        float val[8];
#pragma unroll
        for (int j = 0; j < 8; ++j) {
            int c = col_of(c0a, j);
            float lo = tq.x * lBp[c * RANK + 0] + tq.y * lBp[c * RANK + 1]
                     + tq.z * lBp[c * RANK + 2] + tq.w * lBp[c * RANK + 3];
            val[j] = acc[i][j] + gb[c] + lbp[c] + SCALING_F * lo;
        }
        // LayerNorm across the 16 cg lanes (each holds 8 of 128)
        float ssum = 0.f;
#pragma unroll
        for (int j = 0; j < 8; ++j) ssum += val[j];
#pragma unroll
        for (int m = 8; m >= 1; m >>= 1) ssum += __shfl_xor(ssum, m);
        float mu = ssum * (1.0f / HDIM);
        float vsum = 0.f;
#pragma unroll
        for (int j = 0; j < 8; ++j) { float d = val[j] - mu; vsum += d * d; }
#pragma unroll
        for (int m = 8; m >= 1; m >>= 1) vsum += __shfl_xor(vsum, m);
        float rstd = rsqrtf(vsum * (1.0f / HDIM) + EPS_LN);

        float* ho = h + (size_t)row * HDIM;
        float4 h0 = *(const float4*)(ho + c0a);
        float4 h1 = *(const float4*)(ho + c0a + 64);
        float hold[8] = {h0.x, h0.y, h0.z, h0.w, h1.x, h1.y, h1.z, h1.w};
        float o[8];
#pragma unroll
        for (int j = 0; j < 8; ++j) {
            int c = col_of(c0a, j);
            float y = (val[j] - mu) * rstd * gammap[c] + betap[c];
            float g = 0.5f * y * (1.0f + erff(y * 0.70710678118654752f));
            o[j] = hold[j] + g;
        }
        *(float4*)(ho + c0a)      = make_float4(o[0], o[1], o[2], o[3]);
        *(float4*)(ho + c0a + 64) = make_float4(o[4], o[5], o[6], o[7]);
    }
}

// ================= output projection =================

__global__ __launch_bounds__(256) void out_kernel(
        const float* __restrict__ h,
        const float* __restrict__ W, const float* __restrict__ b,
        const float* __restrict__ A, const float* __restrict__ B,
        float* __restrict__ out, int N) {
    __shared__ float xt[BK][XT_LD];
    __shared__ float wt[BK][WT_LD];
    __shared__ float ts[BM][RANK];
    int brow = blockIdx.x * BM;
    int tid = threadIdx.x;
    int rg = tid >> 4, cg = tid & 15;
    int r0 = rg * 4, c0a = cg * 4;
    int lrow = tid >> 2, lq = tid & 3;

    float acc[4][8] = {};
    float tacc = 0.f;

    for (int k0 = 0; k0 < HDIM; k0 += BK) {
        __syncthreads();
        stage_x(h, HDIM, brow, k0, N, tid, xt);
        stage_wT(W, HDIM, k0, tid, wt);
        __syncthreads();
        tacc += lora_part(xt, A, HDIM, k0, lrow, lq);
        mm_inner(xt, wt, r0, c0a, acc);
    }
    ts[lrow][lq] = tacc;
    __syncthreads();

#pragma unroll
    for (int i = 0; i < 4; ++i) {
        int row = brow + r0 + i;
        if (row >= N) break;
        float4 tq = *(const float4*)&ts[r0 + i][0];
        float o[8];
#pragma unroll
        for (int j = 0; j < 8; ++j) {
            int c = col_of(c0a, j);
            float lo = tq.x * B[c * RANK + 0] + tq.y * B[c * RANK + 1]
                     + tq.z * B[c * RANK + 2] + tq.w * B[c * RANK + 3];
            o[j] = acc[i][j] + b[c] + SCALING_F * lo;
        }
        float* oo = out + (size_t)row * HDIM;
        *(float4*)(oo + c0a)      = make_float4(o[0], o[1], o[2], o[3]);
        *(float4*)(oo + c0a + 64) = make_float4(o[4], o[5], o[6], o[7]);
    }
}

// ================= launch =================

extern "C" void kernel_launch(void* const* d_in, const int* in_sizes, int n_in,
                              void* d_out, int out_size, void* d_ws, size_t ws_size,
                              hipStream_t stream) {
    const float* features = (const float*)d_in[0];
    const int*   esrc     = (const int*)d_in[1];
    const int*   edst     = (const int*)d_in[2];
    const float* pe       = (const float*)d_in[3];
    const float* W_in     = (const float*)d_in[4];
    const float* b_in     = (const float*)d_in[5];
    const float* A_in     = (const float*)d_in[6];
    const float* B_in     = (const float*)d_in[7];
    const float* gnn_W    = (const float*)d_in[8];
    const float* gnn_b    = (const float*)d_in[9];
    const float* lW       = (const float*)d_in[10];
    const float* lb       = (const float*)d_in[11];
    const float* lA       = (const float*)d_in[12];
    const float* lB       = (const float*)d_in[13];
    const float* gamma    = (const float*)d_in[14];
    const float* beta     = (const float*)d_in[15];
    const float* W_out    = (const float*)d_in[16];
    const float* b_out    = (const float*)d_in[17];
    const float* A_out    = (const float*)d_in[18];
    const float* B_out    = (const float*)d_in[19];

    int N = in_sizes[0] / INDIM;   // 100000
    int E = in_sizes[1];           // 1,700,000
    int NB = (N + 255) / 256;

    // workspace layout
    char* ws = (char*)d_ws;
    float* h       = (float*)ws;                               // N*H
    float* agg     = h + (size_t)N * HDIM;                     // N*H
    int*   dego    = (int*)(agg + (size_t)N * HDIM);           // N
    int*   degi    = dego + N;                                 // N
    float* nout    = (float*)(degi + N);                       // N
    float* nin     = nout + N;                                 // N
    int*   row_ptr = (int*)(nin + N);                          // N+1
    int*   cursor  = row_ptr + N + 1;                          // N
    int*   sincl   = cursor + N;                               // N
    int*   bsum    = sincl + N;                                // NB
    int*   csr_src = bsum + NB;                                // E

    hipMemsetAsync(dego, 0, 2 * (size_t)N * sizeof(int), stream);
    deg_kernel<<<(E + 255) / 256, 256, 0, stream>>>(esrc, edst, dego, degi, E);
    norm_kernel<<<NB, 256, 0, stream>>>(dego, degi, nout, nin, N);

    scan1_kernel<<<NB, 256, 0, stream>>>(degi, sincl, bsum, N);
    scan2_kernel<<<1, 512, 0, stream>>>(bsum, NB);
    scan3_kernel<<<NB, 256, 0, stream>>>(degi, sincl, bsum, row_ptr, cursor, N);
    place_kernel<<<(E + 255) / 256, 256, 0, stream>>>(esrc, edst, cursor, csr_src, E);

    int gemm_grid = (N + BM - 1) / BM;   // 1563
    input_kernel<<<gemm_grid, 256, 0, stream>>>(features, pe, W_in, b_in, A_in, B_in, h, N);

    for (int i = 0; i < NLAYER; ++i) {
        gather_kernel<<<(N + 3) / 4, 256, 0, stream>>>(h, nout, nin, row_ptr, csr_src, agg, N);
        layer_kernel<<<gemm_grid, 256, 0, stream>>>(
            h, agg,
            gnn_W + (size_t)i * HDIM * HDIM, gnn_b + (size_t)i * HDIM,
            lW + (size_t)i * HDIM * HDIM, lb + (size_t)i * HDIM,
            lA + (size_t)i * RANK * HDIM, lB + (size_t)i * HDIM * RANK,
            gamma + (size_t)i * HDIM, beta + (size_t)i * HDIM, N);
    }

    out_kernel<<<gemm_grid, 256, 0, stream>>>(h, W_out, b_out, A_out, B_out, (float*)d_out, N);
}